// Round 1
// baseline (290.861 us; speedup 1.0000x reference)
//
#include <hip/hip_runtime.h>
#include <math.h>

#define BATCHN 64
#define MEMN   1024
#define ADDRN  64
#define RHN    4
#define IFW    471
#define OUTC   256

__device__ __forceinline__ float sigm(float x) { return 1.f / (1.f + expf(-x)); }

// ---------------- usage = (u + w - u*w) * prod_r (1 - fg_r * rw_r) ----------
__global__ __launch_bounds__(256) void k_usage(const float* __restrict__ ifc,
                                               const float* __restrict__ rw,
                                               const float* __restrict__ ww,
                                               const float* __restrict__ uv,
                                               float* __restrict__ usage) {
    int g = blockIdx.x * blockDim.x + threadIdx.x;   // [0, 65536)
    if (g >= BATCHN * MEMN) return;
    int b = g >> 10;
    const float* row = ifc + b * IFW;
    float fg0 = sigm(row[192]), fg1 = sigm(row[193]);
    float fg2 = sigm(row[194]), fg3 = sigm(row[195]);
    float4 r = ((const float4*)rw)[g];
    float ret = (1.f - fg0 * r.x) * (1.f - fg1 * r.y) *
                (1.f - fg2 * r.z) * (1.f - fg3 * r.w);
    float u = uv[g], w = ww[g];
    usage[g] = (u + w - u * w) * ret;
}

// ------------- per-batch: bitonic argsort + cumprod scan -> alloc_w ---------
__global__ __launch_bounds__(512) void k_alloc(const float* __restrict__ usage,
                                               float* __restrict__ alloc) {
    __shared__ float sv[1024];
    __shared__ int   si[1024];
    __shared__ float sp[1024];
    __shared__ float st[1024];
    int b = blockIdx.x, tid = threadIdx.x;
    for (int i = tid; i < 1024; i += 512) { sv[i] = usage[b * 1024 + i]; si[i] = i; }
    __syncthreads();
    // bitonic sort ascending, tie-break on original index (== stable argsort)
    for (int k = 2; k <= 1024; k <<= 1) {
        for (int j = k >> 1; j > 0; j >>= 1) {
            for (int i = tid; i < 1024; i += 512) {
                int x = i ^ j;
                if (x > i) {
                    float a = sv[i], c = sv[x];
                    int   ai = si[i], ci = si[x];
                    bool agt = (a > c) || (a == c && ai > ci);
                    bool up  = ((i & k) == 0);
                    if (agt == up) { sv[i] = c; sv[x] = a; si[i] = ci; si[x] = ai; }
                }
            }
            __syncthreads();
        }
    }
    // inclusive product scan (Hillis-Steele, ping-pong)
    for (int i = tid; i < 1024; i += 512) sp[i] = sv[i];
    __syncthreads();
    float* src = sp; float* dst = st;
    for (int off = 1; off < 1024; off <<= 1) {
        for (int i = tid; i < 1024; i += 512)
            dst[i] = (i >= off) ? src[i - off] * src[i] : src[i];
        __syncthreads();
        float* t = src; src = dst; dst = t;
    }
    // alloc_sorted = (1 - u_s) * cumprod(u_s); scatter back via sorted index
    for (int i = tid; i < 1024; i += 512)
        alloc[b * 1024 + si[i]] = (1.f - sv[i]) * src[i];
}

// ---------- sim[b,n] = strength_b * cos(memory[b,n], key_b) -----------------
__global__ __launch_bounds__(256) void k_sim(const float* __restrict__ ifc,
                                             const float* __restrict__ mem,
                                             float* __restrict__ sim) {
    int wid  = (int)((blockIdx.x * (size_t)blockDim.x + threadIdx.x) >> 6);
    int lane = threadIdx.x & 63;
    if (wid >= BATCHN * MEMN) return;
    int b = wid >> 10;
    float k = ifc[b * IFW + lane];                    // lane < 64 == ADDRN
    float m = mem[(size_t)wid * ADDRN + lane];
    float d = m * k, ms = m * m, ks = k * k;
    for (int o = 32; o > 0; o >>= 1) {
        d  += __shfl_xor(d, o, 64);
        ms += __shfl_xor(ms, o, 64);
        ks += __shfl_xor(ks, o, 64);
    }
    if (lane == 0) {
        float x = ifc[b * IFW + 200];
        float strength = 1.f + (fmaxf(x, 0.f) + log1pf(expf(-fabsf(x))));
        float s = d / (sqrtf(ms) * sqrtf(ks) + 1e-6f);
        sim[wid] = s * strength;
    }
}

// --------- per-batch softmax(sim) + gates + alloc -> write_w ----------------
__global__ __launch_bounds__(256) void k_write(const float* __restrict__ ifc,
                                               const float* __restrict__ sim,
                                               const float* __restrict__ alloc,
                                               float* __restrict__ wout) {
    __shared__ float red[256];
    int b = blockIdx.x, tid = threadIdx.x;
    float4 v = ((const float4*)(sim + b * 1024))[tid];
    float lm = fmaxf(fmaxf(v.x, v.y), fmaxf(v.z, v.w));
    red[tid] = lm; __syncthreads();
    for (int o = 128; o > 0; o >>= 1) {
        if (tid < o) red[tid] = fmaxf(red[tid], red[tid + o]);
        __syncthreads();
    }
    float mx = red[0]; __syncthreads();
    float e0 = expf(v.x - mx), e1 = expf(v.y - mx);
    float e2 = expf(v.z - mx), e3 = expf(v.w - mx);
    red[tid] = e0 + e1 + e2 + e3; __syncthreads();
    for (int o = 128; o > 0; o >>= 1) {
        if (tid < o) red[tid] += red[tid + o];
        __syncthreads();
    }
    float inv = 1.f / red[0];
    float wg = sigm(ifc[b * IFW + 201]);
    float ag = sigm(ifc[b * IFW + 202]);
    float4 a = ((const float4*)(alloc + b * 1024))[tid];
    float4 o4;
    o4.x = wg * ((1.f - ag) * (e0 * inv) + ag * a.x);
    o4.y = wg * ((1.f - ag) * (e1 * inv) + ag * a.y);
    o4.z = wg * ((1.f - ag) * (e2 * inv) + ag * a.z);
    o4.w = wg * ((1.f - ag) * (e3 * inv) + ag * a.w);
    ((float4*)(wout + b * 1024))[tid] = o4;
}

// ---------- link update: (1 - w_i + w_j)*L + w_i*p_j, zero diag -------------
__global__ __launch_bounds__(256) void k_link(const float* __restrict__ L,
                                              const float* __restrict__ w,
                                              const float* __restrict__ p,
                                              float* __restrict__ out) {
    size_t n4     = (size_t)BATCHN * MEMN * MEMN / 4;
    size_t stride = (size_t)gridDim.x * blockDim.x;
    for (size_t idx = (size_t)blockIdx.x * blockDim.x + threadIdx.x; idx < n4; idx += stride) {
        size_t f4 = idx * 4;
        int b   = (int)(f4 >> 20);
        int rem = (int)(f4 & ((1u << 20) - 1));
        int i = rem >> 10;
        int j = rem & 1023;          // multiple of 4
        float  wi = w[b * 1024 + i];
        float4 wj = *(const float4*)(w + b * 1024 + j);
        float4 pj = *(const float4*)(p + b * 1024 + j);
        float4 l4 = ((const float4*)L)[idx];
        float4 o;
        o.x = (1.f - wi + wj.x) * l4.x + wi * pj.x;
        o.y = (1.f - wi + wj.y) * l4.y + wi * pj.y;
        o.z = (1.f - wi + wj.z) * l4.z + wi * pj.z;
        o.w = (1.f - wi + wj.w) * l4.w + wi * pj.w;
        if (i >= j && i < j + 4) (&o.x)[i - j] = 0.f;   // diagonal
        ((float4*)out)[idx] = o;
    }
}

// ---------------- memory_output = interface @ W_out + b_out -----------------
__global__ __launch_bounds__(256) void k_gemm(const float* __restrict__ ifc,
                                              const float* __restrict__ Wo,
                                              const float* __restrict__ bo,
                                              float* __restrict__ out) {
    __shared__ float row[IFW];
    int b = blockIdx.x, c = threadIdx.x;
    for (int k = c; k < IFW; k += 256) row[k] = ifc[b * IFW + k];
    __syncthreads();
    float acc = bo[c];
    #pragma unroll 4
    for (int k = 0; k < IFW; ++k) acc += row[k] * Wo[k * OUTC + c];
    out[b * OUTC + c] = acc;
}

extern "C" void kernel_launch(void* const* d_in, const int* in_sizes, int n_in,
                              void* d_out, int out_size, void* d_ws, size_t ws_size,
                              hipStream_t stream) {
    const float* ifc = (const float*)d_in[0];
    const float* mem = (const float*)d_in[1];
    const float* rw  = (const float*)d_in[2];
    const float* ww  = (const float*)d_in[3];
    const float* uv  = (const float*)d_in[4];
    const float* pw  = (const float*)d_in[5];
    const float* lm  = (const float*)d_in[6];
    const float* Wo  = (const float*)d_in[7];
    const float* bo  = (const float*)d_in[8];

    float* out   = (float*)d_out;
    float* mo    = out;                       // 64*256
    float* wwout = out + BATCHN * OUTC;       // 64*1024
    float* lout  = wwout + BATCHN * MEMN;     // 64*1024*1024

    float* ws    = (float*)d_ws;
    float* usage = ws;                        // 65536
    float* alloc = ws + BATCHN * MEMN;        // 65536
    float* simv  = alloc + BATCHN * MEMN;     // 65536

    k_usage<<<(BATCHN * MEMN) / 256, 256, 0, stream>>>(ifc, rw, ww, uv, usage);
    k_alloc<<<BATCHN, 512, 0, stream>>>(usage, alloc);
    k_sim<<<(BATCHN * MEMN) / 4, 256, 0, stream>>>(ifc, mem, simv);
    k_write<<<BATCHN, 256, 0, stream>>>(ifc, simv, alloc, wwout);
    k_link<<<2048, 256, 0, stream>>>(lm, wwout, pw, lout);
    k_gemm<<<BATCHN, 256, 0, stream>>>(ifc, Wo, bo, mo);
}

// Round 4
// 184.800 us; speedup vs baseline: 1.5739x; 1.5739x over previous
//
#include <hip/hip_runtime.h>
#include <math.h>

#define BATCHN 64
#define MEMN   1024
#define ADDRN  64
#define IFW    471
#define OUTC   256

typedef float f4 __attribute__((ext_vector_type(4)));

__device__ __forceinline__ float sigm(float x) { return 1.f / (1.f + expf(-x)); }

// ---- fused: usage -> rank (argsort) -> cumprod scan -> alloc weights -------
// one block per batch, 1024 threads (one per memory slot)
__global__ __launch_bounds__(1024) void k_pre(const float* __restrict__ ifc,
                                              const float* __restrict__ rw,
                                              const float* __restrict__ ww,
                                              const float* __restrict__ uv,
                                              float* __restrict__ alloc) {
    __shared__ float sv[1024];   // usage by original index
    __shared__ float sa[1024];   // sorted / scan ping
    __shared__ float sb[1024];   // scan pong
    int b = blockIdx.x, i = threadIdx.x;
    const float* row = ifc + b * IFW;
    float fg0 = sigm(row[192]), fg1 = sigm(row[193]);
    float fg2 = sigm(row[194]), fg3 = sigm(row[195]);
    float4 r = ((const float4*)rw)[b * 1024 + i];
    float ret = (1.f - fg0 * r.x) * (1.f - fg1 * r.y) *
                (1.f - fg2 * r.z) * (1.f - fg3 * r.w);
    float u = uv[b * 1024 + i], w = ww[b * 1024 + i];
    float vi = (u + w - u * w) * ret;
    sv[i] = vi;
    __syncthreads();
    // rank = #elements strictly less, ties broken by original index (stable)
    int rank = 0;
    #pragma unroll 8
    for (int j = 0; j < 1024; ++j) {
        float vj = sv[j];                       // LDS broadcast
        rank += (vj < vi) || (vj == vi && j < i);
    }
    sa[rank] = vi;                              // scatter into sorted order
    __syncthreads();
    // inclusive product scan over sorted values (Hillis-Steele, ping-pong)
    float* src = sa; float* dst = sb;
    for (int off = 1; off < 1024; off <<= 1) {
        float x = src[i];
        if (i >= off) x *= src[i - off];
        dst[i] = x;
        __syncthreads();
        float* t = src; src = dst; dst = t;
    }
    alloc[b * 1024 + i] = (1.f - vi) * src[rank];
}

// ---------- sim[b,n] = strength_b * cos(memory[b,n], key_b) -----------------
__global__ __launch_bounds__(256) void k_sim(const float* __restrict__ ifc,
                                             const float* __restrict__ mem,
                                             float* __restrict__ sim) {
    int wid  = (int)((blockIdx.x * (size_t)blockDim.x + threadIdx.x) >> 6);
    int lane = threadIdx.x & 63;
    if (wid >= BATCHN * MEMN) return;
    int b = wid >> 10;
    float k = ifc[b * IFW + lane];              // lane < 64 == ADDRN
    float m = mem[(size_t)wid * ADDRN + lane];
    float d = m * k, ms = m * m, ks = k * k;
    for (int o = 32; o > 0; o >>= 1) {
        d  += __shfl_xor(d, o, 64);
        ms += __shfl_xor(ms, o, 64);
        ks += __shfl_xor(ks, o, 64);
    }
    if (lane == 0) {
        float x = ifc[b * IFW + 200];
        float strength = 1.f + (fmaxf(x, 0.f) + log1pf(expf(-fabsf(x))));
        float s = d / (sqrtf(ms) * sqrtf(ks) + 1e-6f);
        sim[wid] = s * strength;
    }
}

// --------- per-batch softmax(sim) + gates + alloc -> write_w ----------------
__global__ __launch_bounds__(256) void k_write(const float* __restrict__ ifc,
                                               const float* __restrict__ sim,
                                               const float* __restrict__ alloc,
                                               float* __restrict__ wout) {
    __shared__ float red[256];
    int b = blockIdx.x, tid = threadIdx.x;
    float4 v = ((const float4*)(sim + b * 1024))[tid];
    float lm = fmaxf(fmaxf(v.x, v.y), fmaxf(v.z, v.w));
    red[tid] = lm; __syncthreads();
    for (int o = 128; o > 0; o >>= 1) {
        if (tid < o) red[tid] = fmaxf(red[tid], red[tid + o]);
        __syncthreads();
    }
    float mx = red[0]; __syncthreads();
    float e0 = expf(v.x - mx), e1 = expf(v.y - mx);
    float e2 = expf(v.z - mx), e3 = expf(v.w - mx);
    red[tid] = e0 + e1 + e2 + e3; __syncthreads();
    for (int o = 128; o > 0; o >>= 1) {
        if (tid < o) red[tid] += red[tid + o];
        __syncthreads();
    }
    float inv = 1.f / red[0];
    float wg = sigm(ifc[b * IFW + 201]);
    float ag = sigm(ifc[b * IFW + 202]);
    float4 a = ((const float4*)(alloc + b * 1024))[tid];
    float4 o4;
    o4.x = wg * ((1.f - ag) * (e0 * inv) + ag * a.x);
    o4.y = wg * ((1.f - ag) * (e1 * inv) + ag * a.y);
    o4.z = wg * ((1.f - ag) * (e2 * inv) + ag * a.z);
    o4.w = wg * ((1.f - ag) * (e3 * inv) + ag * a.w);
    ((float4*)(wout + b * 1024))[tid] = o4;
}

// ---------- link update: one block per (b,i) row, nt store ------------------
__global__ __launch_bounds__(256) void k_link(const float* __restrict__ L,
                                              const float* __restrict__ w,
                                              const float* __restrict__ p,
                                              float* __restrict__ out) {
    int blk = blockIdx.x;                 // = b*1024 + i
    int b = blk >> 10, i = blk & 1023;
    int t = threadIdx.x;                  // float4 column index
    float wi = w[(b << 10) + i];          // uniform -> scalar load
    f4 wj = ((const f4*)(w + (b << 10)))[t];
    f4 pj = ((const f4*)(p + (b << 10)))[t];
    size_t base = ((size_t)blk << 8) + t; // float4 element index
    f4 l4 = ((const f4*)L)[base];
    f4 o = (1.f - wi + wj) * l4 + wi * pj;
    int j0 = t << 2;
    o.x = (j0     == i) ? 0.f : o.x;      // zero diagonal, branchless
    o.y = (j0 + 1 == i) ? 0.f : o.y;
    o.z = (j0 + 2 == i) ? 0.f : o.z;
    o.w = (j0 + 3 == i) ? 0.f : o.w;
    __builtin_nontemporal_store(o, ((f4*)out) + base);
}

// ---------------- memory_output = interface @ W_out + b_out -----------------
__global__ __launch_bounds__(256) void k_gemm(const float* __restrict__ ifc,
                                              const float* __restrict__ Wo,
                                              const float* __restrict__ bo,
                                              float* __restrict__ out) {
    __shared__ float row[IFW];
    int b = blockIdx.x, c = threadIdx.x;
    for (int k = c; k < IFW; k += 256) row[k] = ifc[b * IFW + k];
    __syncthreads();
    float a0 = 0.f, a1 = 0.f, a2 = 0.f, a3 = 0.f;
    #pragma unroll 4
    for (int k = 0; k < 468; k += 4) {
        a0 += row[k]     * Wo[(k)     * OUTC + c];
        a1 += row[k + 1] * Wo[(k + 1) * OUTC + c];
        a2 += row[k + 2] * Wo[(k + 2) * OUTC + c];
        a3 += row[k + 3] * Wo[(k + 3) * OUTC + c];
    }
    for (int k = 468; k < IFW; ++k) a0 += row[k] * Wo[k * OUTC + c];
    out[b * OUTC + c] = (a0 + a1) + (a2 + a3) + bo[c];
}

extern "C" void kernel_launch(void* const* d_in, const int* in_sizes, int n_in,
                              void* d_out, int out_size, void* d_ws, size_t ws_size,
                              hipStream_t stream) {
    const float* ifc = (const float*)d_in[0];
    const float* mem = (const float*)d_in[1];
    const float* rw  = (const float*)d_in[2];
    const float* ww  = (const float*)d_in[3];
    const float* uv  = (const float*)d_in[4];
    const float* pw  = (const float*)d_in[5];
    const float* lm  = (const float*)d_in[6];
    const float* Wo  = (const float*)d_in[7];
    const float* bo  = (const float*)d_in[8];

    float* out   = (float*)d_out;
    float* mo    = out;                       // 64*256
    float* wwout = out + BATCHN * OUTC;       // 64*1024
    float* lout  = wwout + BATCHN * MEMN;     // 64*1024*1024

    float* ws    = (float*)d_ws;
    float* alloc = ws;                        // 65536
    float* simv  = ws + BATCHN * MEMN;        // 65536

    k_pre<<<BATCHN, 1024, 0, stream>>>(ifc, rw, ww, uv, alloc);
    k_sim<<<(BATCHN * MEMN) / 4, 256, 0, stream>>>(ifc, mem, simv);
    k_write<<<BATCHN, 256, 0, stream>>>(ifc, simv, alloc, wwout);
    k_link<<<BATCHN * MEMN, 256, 0, stream>>>(lm, wwout, pw, lout);
    k_gemm<<<BATCHN, 256, 0, stream>>>(ifc, Wo, bo, mo);
}

// Round 5
// 177.118 us; speedup vs baseline: 1.6422x; 1.0434x over previous
//
#include <hip/hip_runtime.h>
#include <math.h>

#define BATCHN 64
#define MEMN   1024
#define ADDRN  64
#define IFW    471
#define OUTC   256

typedef float f4 __attribute__((ext_vector_type(4)));

__device__ __forceinline__ float sigm(float x) { return 1.f / (1.f + expf(-x)); }

// ---- fused: usage -> rank (argsort) -> cumprod scan -> alloc weights -------
// one block per batch, 1024 threads (one per memory slot)
__global__ __launch_bounds__(1024) void k_pre(const float* __restrict__ ifc,
                                              const float* __restrict__ rw,
                                              const float* __restrict__ ww,
                                              const float* __restrict__ uv,
                                              float* __restrict__ alloc) {
    __shared__ float sv[1024];   // usage by original index
    __shared__ float sa[1024];   // sorted / scan ping
    __shared__ float sb[1024];   // scan pong
    int b = blockIdx.x, i = threadIdx.x;
    const float* row = ifc + b * IFW;
    float fg0 = sigm(row[192]), fg1 = sigm(row[193]);
    float fg2 = sigm(row[194]), fg3 = sigm(row[195]);
    float4 r = ((const float4*)rw)[b * 1024 + i];
    float ret = (1.f - fg0 * r.x) * (1.f - fg1 * r.y) *
                (1.f - fg2 * r.z) * (1.f - fg3 * r.w);
    float u = uv[b * 1024 + i], w = ww[b * 1024 + i];
    float vi = (u + w - u * w) * ret;
    sv[i] = vi;
    __syncthreads();
    // rank = #elements strictly less, ties broken by original index (stable)
    int rank = 0;
    #pragma unroll 8
    for (int j = 0; j < 1024; ++j) {
        float vj = sv[j];                       // LDS broadcast
        rank += (vj < vi) || (vj == vi && j < i);
    }
    sa[rank] = vi;                              // scatter into sorted order
    __syncthreads();
    // inclusive product scan (Hillis-Steele, ping-pong)
    float* src = sa; float* dst = sb;
    for (int off = 1; off < 1024; off <<= 1) {
        float x = src[i];
        if (i >= off) x *= src[i - off];
        dst[i] = x;
        __syncthreads();
        float* t = src; src = dst; dst = t;
    }
    alloc[b * 1024 + i] = (1.f - vi) * src[rank];
}

// ---------- sim[b,n] = strength_b * cos(memory[b,n], key_b) -----------------
__global__ __launch_bounds__(256) void k_sim(const float* __restrict__ ifc,
                                             const float* __restrict__ mem,
                                             float* __restrict__ sim) {
    int wid  = (int)((blockIdx.x * (size_t)blockDim.x + threadIdx.x) >> 6);
    int lane = threadIdx.x & 63;
    if (wid >= BATCHN * MEMN) return;
    int b = wid >> 10;
    float k = ifc[b * IFW + lane];              // lane < 64 == ADDRN
    float m = mem[(size_t)wid * ADDRN + lane];
    float d = m * k, ms = m * m, ks = k * k;
    for (int o = 32; o > 0; o >>= 1) {
        d  += __shfl_xor(d, o, 64);
        ms += __shfl_xor(ms, o, 64);
        ks += __shfl_xor(ks, o, 64);
    }
    if (lane == 0) {
        float x = ifc[b * IFW + 200];
        float strength = 1.f + (fmaxf(x, 0.f) + log1pf(expf(-fabsf(x))));
        float s = d / (sqrtf(ms) * sqrtf(ks) + 1e-6f);
        sim[wid] = s * strength;
    }
}

// --------- per-batch softmax(sim) + gates + alloc -> write_w ----------------
__global__ __launch_bounds__(256) void k_write(const float* __restrict__ ifc,
                                               const float* __restrict__ sim,
                                               const float* __restrict__ alloc,
                                               float* __restrict__ wout) {
    __shared__ float red[256];
    int b = blockIdx.x, tid = threadIdx.x;
    float4 v = ((const float4*)(sim + b * 1024))[tid];
    float lm = fmaxf(fmaxf(v.x, v.y), fmaxf(v.z, v.w));
    red[tid] = lm; __syncthreads();
    for (int o = 128; o > 0; o >>= 1) {
        if (tid < o) red[tid] = fmaxf(red[tid], red[tid + o]);
        __syncthreads();
    }
    float mx = red[0]; __syncthreads();
    float e0 = expf(v.x - mx), e1 = expf(v.y - mx);
    float e2 = expf(v.z - mx), e3 = expf(v.w - mx);
    red[tid] = e0 + e1 + e2 + e3; __syncthreads();
    for (int o = 128; o > 0; o >>= 1) {
        if (tid < o) red[tid] += red[tid + o];
        __syncthreads();
    }
    float inv = 1.f / red[0];
    float wg = sigm(ifc[b * IFW + 201]);
    float ag = sigm(ifc[b * IFW + 202]);
    float4 a = ((const float4*)(alloc + b * 1024))[tid];
    float4 o4;
    o4.x = wg * ((1.f - ag) * (e0 * inv) + ag * a.x);
    o4.y = wg * ((1.f - ag) * (e1 * inv) + ag * a.y);
    o4.z = wg * ((1.f - ag) * (e2 * inv) + ag * a.z);
    o4.w = wg * ((1.f - ag) * (e3 * inv) + ag * a.w);
    ((float4*)(wout + b * 1024))[tid] = o4;
}

// ---- link update: block = (batch, 64-row chunk); wj/pj in regs, wi s_load --
__global__ __launch_bounds__(256) void k_link(const float* __restrict__ L,
                                              const float* __restrict__ w,
                                              const float* __restrict__ p,
                                              float* __restrict__ out) {
    int blk = blockIdx.x;                 // 64 batches * 16 row-chunks
    int b  = blk >> 4;
    int rc = blk & 15;
    int t  = threadIdx.x;                 // float4 column index [0,256)
    const float* wb = w + (b << 10);
    f4 wj = ((const f4*)wb)[t];           // loaded once, reused 64x
    f4 pj = ((const f4*)(p + (b << 10)))[t];
    int j0 = t << 2;
    size_t rowbase = ((size_t)b << 18) + ((size_t)rc << 14);  // f4 units
    #pragma unroll 4
    for (int r = 0; r < 64; ++r) {
        int i = (rc << 6) + r;
        float wi = wb[i];                 // block-uniform -> scalar load
        size_t idx = rowbase + ((size_t)r << 8) + t;
        f4 l4 = ((const f4*)L)[idx];
        f4 o = (1.f - wi + wj) * l4 + wi * pj;
        o.x = (j0     == i) ? 0.f : o.x;  // zero diagonal, branchless
        o.y = (j0 + 1 == i) ? 0.f : o.y;
        o.z = (j0 + 2 == i) ? 0.f : o.z;
        o.w = (j0 + 3 == i) ? 0.f : o.w;
        __builtin_nontemporal_store(o, ((f4*)out) + idx);
    }
}

// ---------------- memory_output = interface @ W_out + b_out -----------------
__global__ __launch_bounds__(256) void k_gemm(const float* __restrict__ ifc,
                                              const float* __restrict__ Wo,
                                              const float* __restrict__ bo,
                                              float* __restrict__ out) {
    __shared__ float row[IFW];
    int b = blockIdx.x, c = threadIdx.x;
    for (int k = c; k < IFW; k += 256) row[k] = ifc[b * IFW + k];
    __syncthreads();
    float a0 = 0.f, a1 = 0.f, a2 = 0.f, a3 = 0.f;
    #pragma unroll 4
    for (int k = 0; k < 468; k += 4) {
        a0 += row[k]     * Wo[(k)     * OUTC + c];
        a1 += row[k + 1] * Wo[(k + 1) * OUTC + c];
        a2 += row[k + 2] * Wo[(k + 2) * OUTC + c];
        a3 += row[k + 3] * Wo[(k + 3) * OUTC + c];
    }
    for (int k = 468; k < IFW; ++k) a0 += row[k] * Wo[k * OUTC + c];
    out[b * OUTC + c] = (a0 + a1) + (a2 + a3) + bo[c];
}

extern "C" void kernel_launch(void* const* d_in, const int* in_sizes, int n_in,
                              void* d_out, int out_size, void* d_ws, size_t ws_size,
                              hipStream_t stream) {
    const float* ifc = (const float*)d_in[0];
    const float* mem = (const float*)d_in[1];
    const float* rw  = (const float*)d_in[2];
    const float* ww  = (const float*)d_in[3];
    const float* uv  = (const float*)d_in[4];
    const float* pw  = (const float*)d_in[5];
    const float* lm  = (const float*)d_in[6];
    const float* Wo  = (const float*)d_in[7];
    const float* bo  = (const float*)d_in[8];

    float* out   = (float*)d_out;
    float* mo    = out;                       // 64*256
    float* wwout = out + BATCHN * OUTC;       // 64*1024
    float* lout  = wwout + BATCHN * MEMN;     // 64*1024*1024

    float* ws    = (float*)d_ws;
    float* alloc = ws;                        // 65536
    float* simv  = ws + BATCHN * MEMN;        // 65536

    k_pre<<<BATCHN, 1024, 0, stream>>>(ifc, rw, ww, uv, alloc);
    k_sim<<<(BATCHN * MEMN) / 4, 256, 0, stream>>>(ifc, mem, simv);
    k_write<<<BATCHN, 256, 0, stream>>>(ifc, simv, alloc, wwout);
    k_link<<<BATCHN * 16, 256, 0, stream>>>(lm, wwout, pw, lout);
    k_gemm<<<BATCHN, 256, 0, stream>>>(ifc, Wo, bo, mo);
}